// Round 4
// baseline (143.843 us; speedup 1.0000x reference)
//
#include <hip/hip_runtime.h>
#include <hip/hip_bf16.h>

// QuantizedConv2d: B=8, Cin=Cout=320, H=W=64, K=3, stride=1, pad=1.
// out = scale[co] * conv_zp_padded_int8(x_int, W) + bias_eff[co]
// bias_eff[co] = bias[co] - scale[co]*zp*sum(W[co]); x padded with zp byte.

typedef int v4i __attribute__((ext_vector_type(4)));

typedef const unsigned int __attribute__((address_space(1)))* gas_uptr;
typedef unsigned int __attribute__((address_space(3)))* las_uptr;

#define B_   8
#define CIN  320
#define COUT 320
#define H_   64
#define W_   64
#define HW_  4096
#define HP   66
#define WP   66
#define XPAD_BYTES (B_*HP*WP*CIN)
#define W8_BYTES (COUT*9*CIN)

// ---------------------------------------------------------------------------
// Kernel 1: weight repack int32 [O][I][3][3] -> FRAGMENT-LINEAR int8 layout
//   w8[coT(20)][tap(9)][chunk(5)][lane(64)][16B],  lane = q*16 + colc,
//   holding bytes w_orig[co = coT*16+colc][tap][ci = chunk*64 + q*16 .. +16].
// One B-fragment wave-load = one contiguous aligned 1KiB burst. (unchanged)
__global__ __launch_bounds__(256) void repack_bias_kernel(const int* __restrict__ wint,
                                                          unsigned char* __restrict__ w8,
                                                          const float* __restrict__ wsum,
                                                          const float* __restrict__ scale,
                                                          const float* __restrict__ bias,
                                                          const float* __restrict__ zp_p,
                                                          float* __restrict__ be) {
    int j = blockIdx.x * 256 + threadIdx.x;     // < 230,400 dwords
    if (j < COUT) {
        float s = 0.f;
        #pragma unroll
        for (int tp = 0; tp < 9; ++tp) s += wsum[j*9 + tp];
        be[j] = bias[j] - scale[j] * zp_p[0] * s;
    }
    int co  = j / 720;
    int r   = j - co * 720;                     // tap*80 + d
    int tap = r / 80;
    int d   = r - tap * 80;
    int ci  = d * 4;
    const int* base = wint + (co * CIN + ci) * 9 + tap;
    unsigned b0 = (unsigned)(base[0]  & 0xFF);
    unsigned b1 = (unsigned)(base[9]  & 0xFF);
    unsigned b2 = (unsigned)(base[18] & 0xFF);
    unsigned b3 = (unsigned)(base[27] & 0xFF);
    unsigned dword = b0 | (b1 << 8) | (b2 << 16) | (b3 << 24);

    int coT   = co >> 4;
    int colc  = co & 15;
    int chunk = ci >> 6;
    int q     = (ci >> 4) & 3;
    int dw    = (ci >> 2) & 3;
    int lane  = q * 16 + colc;
    int idx   = (((coT * 9 + tap) * 5 + chunk) * 64 + lane) * 4 + dw;
    ((unsigned*)w8)[idx] = dword;
}

// ---------------------------------------------------------------------------
// Kernel 2: quantize + pad (register transpose; LDS dword writes stride 81).
// (unchanged)
__global__ __launch_bounds__(256) void quant_pad_kernel(const float* __restrict__ x,
                                                        unsigned char* __restrict__ xpad,
                                                        const float* __restrict__ inv_p,
                                                        const float* __restrict__ zp_p) {
    __shared__ __align__(16) unsigned lds[64 * 81];
    int bid = blockIdx.x;
    int b  = bid / HP;
    int ph = bid - b * HP;
    int t  = threadIdx.x;
    float inv = inv_p[0];
    float zp  = zp_p[0];
    int zpi = (int)rintf(zp);
    unsigned zd = ((unsigned)(zpi & 0xFF)) * 0x01010101u;

    unsigned* rowbase = (unsigned*)(xpad + (size_t)((b * HP + ph) * WP) * CIN);

    if (ph == 0 || ph == HP - 1) {
        for (int j = t; j < WP * CIN / 4; j += 256) rowbase[j] = zd;
        return;
    }
    int h = ph - 1;
    const float* xrow = x + (size_t)b * CIN * H_ * W_ + h * W_;
    int wq = t & 15;
    int cg = t >> 4;
    #pragma unroll
    for (int i = 0; i < 5; ++i) {
        int ci0 = i * 64 + cg * 4;
        float4 f[4];
        #pragma unroll
        for (int jj = 0; jj < 4; ++jj)
            f[jj] = *(const float4*)(xrow + (size_t)(ci0 + jj) * HW_ + wq * 4);
        #pragma unroll
        for (int k = 0; k < 4; ++k) {
            unsigned d = 0;
            #pragma unroll
            for (int jj = 0; jj < 4; ++jj) {
                float v = (&f[jj].x)[k];
                float q = rintf(v * inv) + zp;
                q = fminf(fmaxf(q, -128.0f), 127.0f);
                int qi = (int)q;
                d |= ((unsigned)(qi & 0xFF)) << (8 * jj);
            }
            lds[(wq * 4 + k) * 81 + (ci0 >> 2)] = d;
        }
    }
    __syncthreads();
    if (t < 80)            rowbase[t] = zd;
    else if (t < 160)      rowbase[65 * 80 + (t - 80)] = zd;
    for (int j = t; j < 64 * 80; j += 256) {
        int p = j / 80;
        int d = j - p * 80;
        rowbase[80 + j] = lds[p * 81 + d];
    }
}

// ---------------------------------------------------------------------------
// Kernel 3: implicit-GEMM conv, halo tile + 3-deep B pipeline.
// C[32768][320] = A[32768][2880] x B[2880][320]. Tile 128(M) x 160(N),
// 4 waves 2(M)x2(N), wave = 64x80 = 4x5 of 16x16x64 i8.
//
// Round-3 post-mortem: after coalescing B (fragment-linear repack) and
// fixing the LDS swizzle (conflicts -> 0), conv sat at 42us with
// MfmaUtil 27 / VALUBusy 14 -- both pipes idle = still latency-bound.
// Stall arithmetic: ~1,400 cy/tap exposed ~= one L2/L3 round trip; the
// 1-tap-deep B prefetch gives only one (already-stalled) MFMA cluster of
// cover. This version: 3-deep B pipeline (bC/bN/bN2 live; issue b(tp+3)
// at tap tp; taps 6..8 issue next chunk's b0/b1/b2, completed for free by
// the chunk barrier's vmcnt drain). Also fixes the vmcnt FIFO interplay:
// first B consumed after the staging issue is b3 (issued tap0), so the
// forced staging drain now has ~3 taps of cover. A stays 1-deep (ds_read
// ~120cy, covered by one cluster).
#define CHUNK_SLOTS 1056           // 4 rows * 66 cols * 4 sub-chunks
#define ROUNDS 5                   // ceil(1056 / 256)
#define BUF_BYTES (ROUNDS * 256 * 16)   // 20,480 B per buffer

__global__ __launch_bounds__(256, 2) void conv_gemm_kernel(const unsigned char* __restrict__ xpad,
                                                           const unsigned char* __restrict__ w8,
                                                           const float* __restrict__ scale,
                                                           const float* __restrict__ be,
                                                           float* __restrict__ out) {
    __shared__ __align__(16) unsigned char Al[2 * BUF_BYTES];   // 40,960 B

    int t    = threadIdx.x;
    int lane = t & 63;
    int wave = t >> 6;
    int wm   = wave & 1;           // M half (64 pixels)
    int wn   = wave >> 1;          // N half (80 couts)
    int m0   = blockIdx.x * 128;   // M fastest; N-pair blocks differ by 256 = same XCD
    int n0   = blockIdx.y * 160;
    int b0   = m0 >> 12;
    int h0   = (m0 & 4095) >> 6;   // first output row of this 2-row tile

    // --- staging source offsets: slot = r*256+t -> (R,C,ql); source sub-chunk
    //     pre-swizzled: qs = ql ^ ((C>>1)&3). Slots >= 1056 clamp to slot 0.
    int srcoff[ROUNDS];
    #pragma unroll
    for (int r = 0; r < ROUNDS; ++r) {
        int slot = r * 256 + t;
        if (slot >= CHUNK_SLOTS) slot = 0;
        int R   = slot / 264;                 // 66 cols * 4 sub-chunks per row
        int rem = slot - R * 264;
        int C   = rem >> 2;
        int ql  = rem & 3;
        int qs  = ql ^ ((C >> 1) & 3);
        srcoff[r] = ((b0 * HP + h0 + R) * WP + C) * CIN + qs * 16;
    }

    int colc = lane & 15;
    int q    = lane >> 4;

    // --- A fragment LDS offsets (per kw, per mi); row term (wm+kh)*4224 added
    //     at use. Phase-uniform swizzle: within any 16-lane quarter-wave,
    //     slot-group = 4(C&1) + q^((C>>1)&3) covers all 8 bank-groups twice.
    int aoffs[3][4];
    #pragma unroll
    for (int kw = 0; kw < 3; ++kw)
        #pragma unroll
        for (int mi = 0; mi < 4; ++mi) {
            int C = mi * 16 + colc + kw;
            aoffs[kw][mi] = C * 64 + ((q ^ ((C >> 1) & 3)) * 16);
        }

    // --- B fragment base pointers: fragment-linear w8, one contiguous 1KiB
    //     per (coT, tap, chunk); offset (tap*5+chunk)*1024 at use.
    const unsigned char* bbase[5];
    int coT0 = (n0 >> 4) + wn * 5;
    #pragma unroll
    for (int ni = 0; ni < 5; ++ni)
        bbase[ni] = w8 + (size_t)(coT0 + ni) * (45 * 1024) + lane * 16;

    v4i acc[4][5];
    v4i zero = {0, 0, 0, 0};
    #pragma unroll
    for (int mi = 0; mi < 4; ++mi)
        #pragma unroll
        for (int ni = 0; ni < 5; ++ni) acc[mi][ni] = zero;

    // --- prologue: B(tap0/1/2, chunk0) prefetch + stage ci-chunk 0 ---
    v4i bC[5], bN[5], bN2[5], aC[4], aN[4];
    #pragma unroll
    for (int ni = 0; ni < 5; ++ni) bC[ni]  = *(const v4i*)(bbase[ni]);
    #pragma unroll
    for (int ni = 0; ni < 5; ++ni) bN[ni]  = *(const v4i*)(bbase[ni] + 5 * 1024);
    #pragma unroll
    for (int ni = 0; ni < 5; ++ni) bN2[ni] = *(const v4i*)(bbase[ni] + 10 * 1024);
    #pragma unroll
    for (int r = 0; r < ROUNDS; ++r)
        __builtin_amdgcn_global_load_lds((gas_uptr)(const void*)(xpad + srcoff[r]),
                                         (las_uptr)(Al + r * 4096 + t * 16), 16, 0, 0);
    __syncthreads();

    #pragma unroll 1
    for (int c = 0; c < 5; ++c) {
        // issue next chunk's staging into the other buffer; latency covered by
        // this chunk's 180 MFMAs before the end-of-loop barrier drain.
        if (c < 4) {
            unsigned char* dst = Al + ((c + 1) & 1) * BUF_BYTES;
            int ci = (c + 1) * 64;
            #pragma unroll
            for (int r = 0; r < ROUNDS; ++r)
                __builtin_amdgcn_global_load_lds((gas_uptr)(const void*)(xpad + srcoff[r] + ci),
                                                 (las_uptr)(dst + r * 4096 + t * 16), 16, 0, 0);
        }
        const unsigned char* ab = Al + (c & 1) * BUF_BYTES;

        // A(tap0): the only non-pipelined ds_read per chunk.
        #pragma unroll
        for (int mi = 0; mi < 4; ++mi)
            aC[mi] = *(const v4i*)(ab + wm * 4224 + aoffs[0][mi]);

        #pragma unroll
        for (int tp = 0; tp < 9; ++tp) {
            // --- B prefetch, 3 taps ahead (crosses the chunk boundary) ---
            v4i bT[5];
            if (tp < 6) {
                #pragma unroll
                for (int ni = 0; ni < 5; ++ni)
                    bT[ni] = *(const v4i*)(bbase[ni] + ((tp + 3) * 5 + c) * 1024);
            } else if (c < 4) {
                #pragma unroll
                for (int ni = 0; ni < 5; ++ni)
                    bT[ni] = *(const v4i*)(bbase[ni] + ((tp - 6) * 5 + (c + 1)) * 1024);
            }
            // --- A prefetch, 1 tap ahead ---
            if (tp < 8) {
                int tn  = tp + 1;
                int kh2 = tn / 3;
                int kw2 = tn - kh2 * 3;
                #pragma unroll
                for (int mi = 0; mi < 4; ++mi)
                    aN[mi] = *(const v4i*)(ab + (wm + kh2) * 4224 + aoffs[kw2][mi]);
            }
            // --- consume current tap ---
            #pragma unroll
            for (int mi = 0; mi < 4; ++mi)
                #pragma unroll
                for (int ni = 0; ni < 5; ++ni)
                    acc[mi][ni] = __builtin_amdgcn_mfma_i32_16x16x64_i8(aC[mi], bC[ni], acc[mi][ni], 0, 0, 0);
            // --- rotate (SSA rename after unroll; all indices static) ---
            if (tp < 8) {
                #pragma unroll
                for (int mi = 0; mi < 4; ++mi) aC[mi] = aN[mi];
            }
            #pragma unroll
            for (int ni = 0; ni < 5; ++ni) bC[ni] = bN[ni];
            #pragma unroll
            for (int ni = 0; ni < 5; ++ni) bN[ni] = bN2[ni];
            if (tp < 6 || c < 4) {
                #pragma unroll
                for (int ni = 0; ni < 5; ++ni) bN2[ni] = bT[ni];
            }
        }
        __syncthreads();   // all reads of buf[c&1] done; stage(c+1) drained
    }

    // Epilogue: C/D layout col = lane&15 (co), row = q*4 + reg (pixel).
    #pragma unroll
    for (int ni = 0; ni < 5; ++ni) {
        int co = n0 + wn * 80 + ni * 16 + colc;
        float s  = scale[co];
        float bz = be[co];
        #pragma unroll
        for (int mi = 0; mi < 4; ++mi) {
            int pix = m0 + wm * 64 + mi * 16 + q * 4;
            int bb2 = pix >> 12;
            int hw  = pix & 4095;
            v4i v = acc[mi][ni];
            float4 o;
            o.x = s * (float)v.x + bz;
            o.y = s * (float)v.y + bz;
            o.z = s * (float)v.z + bz;
            o.w = s * (float)v.w + bz;
            *(float4*)(out + (size_t)(bb2 * COUT + co) * HW_ + hw) = o;
        }
    }
}

// ---------------------------------------------------------------------------
extern "C" void kernel_launch(void* const* d_in, const int* in_sizes, int n_in,
                              void* d_out, int out_size, void* d_ws, size_t ws_size,
                              hipStream_t stream) {
    const float* x     = (const float*)d_in[0];
    const int*   wint  = (const int*)d_in[1];
    const float* wsum  = (const float*)d_in[2];
    const float* scale = (const float*)d_in[3];
    const float* inv_p = (const float*)d_in[4];
    const float* zp_p  = (const float*)d_in[5];
    const float* bias  = (const float*)d_in[6];
    float* out = (float*)d_out;

    unsigned char* xpad = (unsigned char*)d_ws;
    unsigned char* w8   = xpad + XPAD_BYTES;
    float*         be   = (float*)(w8 + W8_BYTES);

    repack_bias_kernel<<<(COUT * 720) / 256, 256, 0, stream>>>(wint, w8, wsum, scale, bias, zp_p, be);
    quant_pad_kernel<<<B_ * HP, 256, 0, stream>>>(x, xpad, inv_p, zp_p);

    dim3 grid((B_ * H_ * W_) / 128, COUT / 160);      // 256 x 2, M fastest
    conv_gemm_kernel<<<grid, 256, 0, stream>>>(xpad, w8, scale, be, out);
}

// Round 5
// 136.003 us; speedup vs baseline: 1.0576x; 1.0576x over previous
//
#include <hip/hip_runtime.h>
#include <hip/hip_bf16.h>

// QuantizedConv2d: B=8, Cin=Cout=320, H=W=64, K=3, stride=1, pad=1.
// out = scale[co] * conv_zp_padded_int8(x_int, W) + bias_eff[co]
// bias_eff[co] = bias[co] - scale[co]*zp*sum(W[co]); x padded with zp byte.

typedef int v4i __attribute__((ext_vector_type(4)));

typedef const unsigned int __attribute__((address_space(1)))* gas_uptr;
typedef unsigned int __attribute__((address_space(3)))* las_uptr;

#define B_   8
#define CIN  320
#define COUT 320
#define H_   64
#define W_   64
#define HW_  4096
#define HP   66
#define WP   66
#define XPAD_BYTES (B_*HP*WP*CIN)
#define W8_BYTES (COUT*9*CIN)

// ---------------------------------------------------------------------------
// Kernel 1: weight repack int32 [O][I][3][3] -> FRAGMENT-LINEAR int8 layout
//   w8[coT(20)][tap(9)][chunk(5)][lane(64)][16B],  lane = q*16 + colc,
//   holding bytes w_orig[co = coT*16+colc][tap][ci = chunk*64 + q*16 .. +16].
// One B-fragment wave-load = one contiguous aligned 1KiB burst. (unchanged)
__global__ __launch_bounds__(256) void repack_bias_kernel(const int* __restrict__ wint,
                                                          unsigned char* __restrict__ w8,
                                                          const float* __restrict__ wsum,
                                                          const float* __restrict__ scale,
                                                          const float* __restrict__ bias,
                                                          const float* __restrict__ zp_p,
                                                          float* __restrict__ be) {
    int j = blockIdx.x * 256 + threadIdx.x;     // < 230,400 dwords
    if (j < COUT) {
        float s = 0.f;
        #pragma unroll
        for (int tp = 0; tp < 9; ++tp) s += wsum[j*9 + tp];
        be[j] = bias[j] - scale[j] * zp_p[0] * s;
    }
    int co  = j / 720;
    int r   = j - co * 720;                     // tap*80 + d
    int tap = r / 80;
    int d   = r - tap * 80;
    int ci  = d * 4;
    const int* base = wint + (co * CIN + ci) * 9 + tap;
    unsigned b0 = (unsigned)(base[0]  & 0xFF);
    unsigned b1 = (unsigned)(base[9]  & 0xFF);
    unsigned b2 = (unsigned)(base[18] & 0xFF);
    unsigned b3 = (unsigned)(base[27] & 0xFF);
    unsigned dword = b0 | (b1 << 8) | (b2 << 16) | (b3 << 24);

    int coT   = co >> 4;
    int colc  = co & 15;
    int chunk = ci >> 6;
    int q     = (ci >> 4) & 3;
    int dw    = (ci >> 2) & 3;
    int lane  = q * 16 + colc;
    int idx   = (((coT * 9 + tap) * 5 + chunk) * 64 + lane) * 4 + dw;
    ((unsigned*)w8)[idx] = dword;
}

// ---------------------------------------------------------------------------
// Kernel 2: quantize + pad (register transpose; LDS dword writes stride 81).
// (unchanged)
__global__ __launch_bounds__(256) void quant_pad_kernel(const float* __restrict__ x,
                                                        unsigned char* __restrict__ xpad,
                                                        const float* __restrict__ inv_p,
                                                        const float* __restrict__ zp_p) {
    __shared__ __align__(16) unsigned lds[64 * 81];
    int bid = blockIdx.x;
    int b  = bid / HP;
    int ph = bid - b * HP;
    int t  = threadIdx.x;
    float inv = inv_p[0];
    float zp  = zp_p[0];
    int zpi = (int)rintf(zp);
    unsigned zd = ((unsigned)(zpi & 0xFF)) * 0x01010101u;

    unsigned* rowbase = (unsigned*)(xpad + (size_t)((b * HP + ph) * WP) * CIN);

    if (ph == 0 || ph == HP - 1) {
        for (int j = t; j < WP * CIN / 4; j += 256) rowbase[j] = zd;
        return;
    }
    int h = ph - 1;
    const float* xrow = x + (size_t)b * CIN * H_ * W_ + h * W_;
    int wq = t & 15;
    int cg = t >> 4;
    #pragma unroll
    for (int i = 0; i < 5; ++i) {
        int ci0 = i * 64 + cg * 4;
        float4 f[4];
        #pragma unroll
        for (int jj = 0; jj < 4; ++jj)
            f[jj] = *(const float4*)(xrow + (size_t)(ci0 + jj) * HW_ + wq * 4);
        #pragma unroll
        for (int k = 0; k < 4; ++k) {
            unsigned d = 0;
            #pragma unroll
            for (int jj = 0; jj < 4; ++jj) {
                float v = (&f[jj].x)[k];
                float q = rintf(v * inv) + zp;
                q = fminf(fmaxf(q, -128.0f), 127.0f);
                int qi = (int)q;
                d |= ((unsigned)(qi & 0xFF)) << (8 * jj);
            }
            lds[(wq * 4 + k) * 81 + (ci0 >> 2)] = d;
        }
    }
    __syncthreads();
    if (t < 80)            rowbase[t] = zd;
    else if (t < 160)      rowbase[65 * 80 + (t - 80)] = zd;
    for (int j = t; j < 64 * 80; j += 256) {
        int p = j / 80;
        int d = j - p * 80;
        rowbase[80 + j] = lds[p * 81 + d];
    }
}

// ---------------------------------------------------------------------------
// Kernel 3: implicit-GEMM conv, halo tile + CLEAN 3-deep B pipeline.
// C[32768][320] = A[32768][2880] x B[2880][320]. Tile 128(M) x 160(N),
// 4 waves 2(M)x2(N), wave = 64x80 = 4x5 of 16x16x64 i8.
//
// Round-4 post-mortem: 3-deep B pipeline REGRESSED (42->51us) because
// (a) the rotate was guarded by a RUNTIME condition (c<4), pinning bN2 to
//     physical regs -> real v_mov chains + blocked load hoisting (the
//     pipeline collapsed to ~0-deep with overhead), and
// (b) staging was issued before the in-chunk B loads, so vmcnt's in-order
//     FIFO made early B consumption wait out the whole staging.
// This version keeps round-3's structure but makes the 3-deep pipeline
// codegen-clean: last chunk PEELED (all rotate guards compile-time),
// staging issued at tap 0 AFTER b3's issue (no in-chunk B behind staging;
// b4's cover = 3 MFMA clusters ~1.6kcy >= staging), next-chunk b0..b2
// issued at taps 6..8 and completed by the barrier's vmcnt drain.
#define CHUNK_SLOTS 1056           // 4 rows * 66 cols * 4 sub-chunks
#define ROUNDS 5                   // ceil(1056 / 256)
#define BUF_BYTES (ROUNDS * 256 * 16)   // 20,480 B per buffer

// One chunk's compute. LAST_ must be a literal 0/1 so every guard below is
// compile-time (tp is unroll-constant): rotations stay SSA renames.
#define CHUNK_BODY(c_, LAST_)                                                   \
{                                                                               \
    const int c__ = (c_);                                                       \
    const unsigned char* ab = Al + (c__ & 1) * BUF_BYTES;                       \
    /* A(tap0): chunk-start ds_read; latency covered by b3+staging issue. */    \
    _Pragma("unroll")                                                           \
    for (int mi = 0; mi < 4; ++mi)                                              \
        aC[mi] = *(const v4i*)(ab + wm * 4224 + aoffs[0][mi]);                  \
    _Pragma("unroll")                                                           \
    for (int tp = 0; tp < 9; ++tp) {                                            \
        v4i bT[5];                                                              \
        if (tp < 6) {               /* b(tp+3) of this chunk */                 \
            _Pragma("unroll")                                                   \
            for (int ni = 0; ni < 5; ++ni)                                      \
                bT[ni] = *(const v4i*)(bbase[ni] + ((tp + 3) * 5 + c__) * 1024);\
        } else if (!LAST_) {        /* b(tp-6) of next chunk */                 \
            _Pragma("unroll")                                                   \
            for (int ni = 0; ni < 5; ++ni)                                      \
                bT[ni] = *(const v4i*)(bbase[ni] + ((tp - 6) * 5 + (c__ + 1)) * 1024);\
        }                                                                       \
        if (!LAST_ && tp == 0) {    /* stage chunk c+1 AFTER b3's issue */      \
            unsigned char* dst = Al + ((c__ + 1) & 1) * BUF_BYTES;              \
            int cio = (c__ + 1) * 64;                                           \
            _Pragma("unroll")                                                   \
            for (int r = 0; r < ROUNDS; ++r)                                    \
                __builtin_amdgcn_global_load_lds(                               \
                    (gas_uptr)(const void*)(xpad + srcoff[r] + cio),            \
                    (las_uptr)(dst + r * 4096 + t * 16), 16, 0, 0);             \
        }                                                                       \
        if (tp < 8) {               /* A 1-deep prefetch */                     \
            int tn  = tp + 1;                                                   \
            int kh2 = tn / 3;                                                   \
            int kw2 = tn - kh2 * 3;                                             \
            _Pragma("unroll")                                                   \
            for (int mi = 0; mi < 4; ++mi)                                      \
                aN[mi] = *(const v4i*)(ab + (wm + kh2) * 4224 + aoffs[kw2][mi]);\
        }                                                                       \
        _Pragma("unroll")                                                       \
        for (int mi = 0; mi < 4; ++mi)                                          \
            _Pragma("unroll")                                                   \
            for (int ni = 0; ni < 5; ++ni)                                      \
                acc[mi][ni] = __builtin_amdgcn_mfma_i32_16x16x64_i8(            \
                    aC[mi], bC[ni], acc[mi][ni], 0, 0, 0);                      \
        /* rotations: ALL guards compile-time -> pure renames */                \
        if (tp < 8) {                                                           \
            _Pragma("unroll")                                                   \
            for (int mi = 0; mi < 4; ++mi) aC[mi] = aN[mi];                     \
        }                                                                       \
        _Pragma("unroll")                                                       \
        for (int ni = 0; ni < 5; ++ni) bC[ni] = bN[ni];                         \
        _Pragma("unroll")                                                       \
        for (int ni = 0; ni < 5; ++ni) bN[ni] = bN2[ni];                        \
        if (tp < 6 || !LAST_) {                                                 \
            _Pragma("unroll")                                                   \
            for (int ni = 0; ni < 5; ++ni) bN2[ni] = bT[ni];                    \
        }                                                                       \
    }                                                                           \
}

__global__ __launch_bounds__(256, 2) void conv_gemm_kernel(const unsigned char* __restrict__ xpad,
                                                           const unsigned char* __restrict__ w8,
                                                           const float* __restrict__ scale,
                                                           const float* __restrict__ be,
                                                           float* __restrict__ out) {
    __shared__ __align__(16) unsigned char Al[2 * BUF_BYTES];   // 40,960 B

    int t    = threadIdx.x;
    int lane = t & 63;
    int wave = t >> 6;
    int wm   = wave & 1;           // M half (64 pixels)
    int wn   = wave >> 1;          // N half (80 couts)
    int m0   = blockIdx.x * 128;   // M fastest; N-pair blocks differ by 256 = same XCD
    int n0   = blockIdx.y * 160;
    int b0   = m0 >> 12;
    int h0   = (m0 & 4095) >> 6;   // first output row of this 2-row tile

    // --- staging source offsets: slot = r*256+t -> (R,C,ql); source sub-chunk
    //     pre-swizzled: qs = ql ^ ((C>>1)&3). Slots >= 1056 clamp to slot 0.
    int srcoff[ROUNDS];
    #pragma unroll
    for (int r = 0; r < ROUNDS; ++r) {
        int slot = r * 256 + t;
        if (slot >= CHUNK_SLOTS) slot = 0;
        int R   = slot / 264;                 // 66 cols * 4 sub-chunks per row
        int rem = slot - R * 264;
        int C   = rem >> 2;
        int ql  = rem & 3;
        int qs  = ql ^ ((C >> 1) & 3);
        srcoff[r] = ((b0 * HP + h0 + R) * WP + C) * CIN + qs * 16;
    }

    int colc = lane & 15;
    int q    = lane >> 4;

    // --- A fragment LDS offsets (per kw, per mi); row term (wm+kh)*4224 added
    //     at use. Phase-uniform swizzle: within any 16-lane quarter-wave,
    //     slot-group = 4(C&1) + q^((C>>1)&3) covers all 8 bank-groups twice.
    int aoffs[3][4];
    #pragma unroll
    for (int kw = 0; kw < 3; ++kw)
        #pragma unroll
        for (int mi = 0; mi < 4; ++mi) {
            int C = mi * 16 + colc + kw;
            aoffs[kw][mi] = C * 64 + ((q ^ ((C >> 1) & 3)) * 16);
        }

    // --- B fragment base pointers: fragment-linear w8, one contiguous 1KiB
    //     per (coT, tap, chunk); offset (tap*5+chunk)*1024 at use.
    const unsigned char* bbase[5];
    int coT0 = (n0 >> 4) + wn * 5;
    #pragma unroll
    for (int ni = 0; ni < 5; ++ni)
        bbase[ni] = w8 + (size_t)(coT0 + ni) * (45 * 1024) + lane * 16;

    v4i acc[4][5];
    v4i zero = {0, 0, 0, 0};
    #pragma unroll
    for (int mi = 0; mi < 4; ++mi)
        #pragma unroll
        for (int ni = 0; ni < 5; ++ni) acc[mi][ni] = zero;

    // --- prologue: B(tap0/1/2, chunk0) prefetch + stage ci-chunk 0 ---
    v4i bC[5], bN[5], bN2[5], aC[4], aN[4];
    #pragma unroll
    for (int ni = 0; ni < 5; ++ni) bC[ni]  = *(const v4i*)(bbase[ni]);
    #pragma unroll
    for (int ni = 0; ni < 5; ++ni) bN[ni]  = *(const v4i*)(bbase[ni] + 5 * 1024);
    #pragma unroll
    for (int ni = 0; ni < 5; ++ni) bN2[ni] = *(const v4i*)(bbase[ni] + 10 * 1024);
    #pragma unroll
    for (int r = 0; r < ROUNDS; ++r)
        __builtin_amdgcn_global_load_lds((gas_uptr)(const void*)(xpad + srcoff[r]),
                                         (las_uptr)(Al + r * 4096 + t * 16), 16, 0, 0);
    __syncthreads();

    #pragma unroll 1
    for (int c = 0; c < 4; ++c) {
        CHUNK_BODY(c, 0)
        __syncthreads();   // reads of buf[c&1] done; stage(c+1) + b0..b2 drained
    }
    CHUNK_BODY(4, 1)       // peeled: no staging, no next-chunk B, static guards

    // Epilogue: C/D layout col = lane&15 (co), row = q*4 + reg (pixel).
    #pragma unroll
    for (int ni = 0; ni < 5; ++ni) {
        int co = n0 + wn * 80 + ni * 16 + colc;
        float s  = scale[co];
        float bz = be[co];
        #pragma unroll
        for (int mi = 0; mi < 4; ++mi) {
            int pix = m0 + wm * 64 + mi * 16 + q * 4;
            int bb2 = pix >> 12;
            int hw  = pix & 4095;
            v4i v = acc[mi][ni];
            float4 o;
            o.x = s * (float)v.x + bz;
            o.y = s * (float)v.y + bz;
            o.z = s * (float)v.z + bz;
            o.w = s * (float)v.w + bz;
            *(float4*)(out + (size_t)(bb2 * COUT + co) * HW_ + hw) = o;
        }
    }
}

// ---------------------------------------------------------------------------
extern "C" void kernel_launch(void* const* d_in, const int* in_sizes, int n_in,
                              void* d_out, int out_size, void* d_ws, size_t ws_size,
                              hipStream_t stream) {
    const float* x     = (const float*)d_in[0];
    const int*   wint  = (const int*)d_in[1];
    const float* wsum  = (const float*)d_in[2];
    const float* scale = (const float*)d_in[3];
    const float* inv_p = (const float*)d_in[4];
    const float* zp_p  = (const float*)d_in[5];
    const float* bias  = (const float*)d_in[6];
    float* out = (float*)d_out;

    unsigned char* xpad = (unsigned char*)d_ws;
    unsigned char* w8   = xpad + XPAD_BYTES;
    float*         be   = (float*)(w8 + W8_BYTES);

    repack_bias_kernel<<<(COUT * 720) / 256, 256, 0, stream>>>(wint, w8, wsum, scale, bias, zp_p, be);
    quant_pad_kernel<<<B_ * HP, 256, 0, stream>>>(x, xpad, inv_p, zp_p);

    dim3 grid((B_ * H_ * W_) / 128, COUT / 160);      // 256 x 2, M fastest
    conv_gemm_kernel<<<grid, 256, 0, stream>>>(xpad, w8, scale, be, out);
}

// Round 6
// 134.947 us; speedup vs baseline: 1.0659x; 1.0078x over previous
//
#include <hip/hip_runtime.h>
#include <hip/hip_bf16.h>

// QuantizedConv2d: B=8, Cin=Cout=320, H=W=64, K=3, stride=1, pad=1.
// out = scale[co] * conv_zp_padded_int8(x_int, W) + bias_eff[co]
// bias_eff[co] = bias[co] - scale[co]*zp*sum(W[co]); x padded with zp byte.

typedef int v4i __attribute__((ext_vector_type(4)));

typedef const unsigned int __attribute__((address_space(1)))* gas_uptr;
typedef unsigned int __attribute__((address_space(3)))* las_uptr;

#define B_   8
#define CIN  320
#define COUT 320
#define H_   64
#define W_   64
#define HW_  4096
#define HP   66
#define WP   66
#define XPAD_BYTES (B_*HP*WP*CIN)
#define W8_BYTES (COUT*9*CIN)

// ---------------------------------------------------------------------------
// Kernel 1: weight repack int32 [O][I][3][3] -> FRAGMENT-LINEAR int8 layout
//   w8[coT(20)][tap(9)][chunk(5)][lane(64)][16B],  lane = q*16 + colc,
//   holding bytes w_orig[co = coT*16+colc][tap][ci = chunk*64 + q*16 .. +16].
// One B-fragment wave-load = one contiguous aligned 1KiB burst. (unchanged)
__global__ __launch_bounds__(256) void repack_bias_kernel(const int* __restrict__ wint,
                                                          unsigned char* __restrict__ w8,
                                                          const float* __restrict__ wsum,
                                                          const float* __restrict__ scale,
                                                          const float* __restrict__ bias,
                                                          const float* __restrict__ zp_p,
                                                          float* __restrict__ be) {
    int j = blockIdx.x * 256 + threadIdx.x;     // < 230,400 dwords
    if (j < COUT) {
        float s = 0.f;
        #pragma unroll
        for (int tp = 0; tp < 9; ++tp) s += wsum[j*9 + tp];
        be[j] = bias[j] - scale[j] * zp_p[0] * s;
    }
    int co  = j / 720;
    int r   = j - co * 720;                     // tap*80 + d
    int tap = r / 80;
    int d   = r - tap * 80;
    int ci  = d * 4;
    const int* base = wint + (co * CIN + ci) * 9 + tap;
    unsigned b0 = (unsigned)(base[0]  & 0xFF);
    unsigned b1 = (unsigned)(base[9]  & 0xFF);
    unsigned b2 = (unsigned)(base[18] & 0xFF);
    unsigned b3 = (unsigned)(base[27] & 0xFF);
    unsigned dword = b0 | (b1 << 8) | (b2 << 16) | (b3 << 24);

    int coT   = co >> 4;
    int colc  = co & 15;
    int chunk = ci >> 6;
    int q     = (ci >> 4) & 3;
    int dw    = (ci >> 2) & 3;
    int lane  = q * 16 + colc;
    int idx   = (((coT * 9 + tap) * 5 + chunk) * 64 + lane) * 4 + dw;
    ((unsigned*)w8)[idx] = dword;
}

// ---------------------------------------------------------------------------
// Kernel 2: quantize + pad (register transpose; LDS dword writes stride 81).
// (unchanged)
__global__ __launch_bounds__(256) void quant_pad_kernel(const float* __restrict__ x,
                                                        unsigned char* __restrict__ xpad,
                                                        const float* __restrict__ inv_p,
                                                        const float* __restrict__ zp_p) {
    __shared__ __align__(16) unsigned lds[64 * 81];
    int bid = blockIdx.x;
    int b  = bid / HP;
    int ph = bid - b * HP;
    int t  = threadIdx.x;
    float inv = inv_p[0];
    float zp  = zp_p[0];
    int zpi = (int)rintf(zp);
    unsigned zd = ((unsigned)(zpi & 0xFF)) * 0x01010101u;

    unsigned* rowbase = (unsigned*)(xpad + (size_t)((b * HP + ph) * WP) * CIN);

    if (ph == 0 || ph == HP - 1) {
        for (int j = t; j < WP * CIN / 4; j += 256) rowbase[j] = zd;
        return;
    }
    int h = ph - 1;
    const float* xrow = x + (size_t)b * CIN * H_ * W_ + h * W_;
    int wq = t & 15;
    int cg = t >> 4;
    #pragma unroll
    for (int i = 0; i < 5; ++i) {
        int ci0 = i * 64 + cg * 4;
        float4 f[4];
        #pragma unroll
        for (int jj = 0; jj < 4; ++jj)
            f[jj] = *(const float4*)(xrow + (size_t)(ci0 + jj) * HW_ + wq * 4);
        #pragma unroll
        for (int k = 0; k < 4; ++k) {
            unsigned d = 0;
            #pragma unroll
            for (int jj = 0; jj < 4; ++jj) {
                float v = (&f[jj].x)[k];
                float q = rintf(v * inv) + zp;
                q = fminf(fmaxf(q, -128.0f), 127.0f);
                int qi = (int)q;
                d |= ((unsigned)(qi & 0xFF)) << (8 * jj);
            }
            lds[(wq * 4 + k) * 81 + (ci0 >> 2)] = d;
        }
    }
    __syncthreads();
    if (t < 80)            rowbase[t] = zd;
    else if (t < 160)      rowbase[65 * 80 + (t - 80)] = zd;
    for (int j = t; j < 64 * 80; j += 256) {
        int p = j / 80;
        int d = j - p * 80;
        rowbase[80 + j] = lds[p * 81 + d];
    }
}

// ---------------------------------------------------------------------------
// Kernel 3: implicit-GEMM conv, halo tile + 3-deep B / 2-deep A pipeline
//           + T5 s_setprio wave anti-phasing.
// C[32768][320] = A[32768][2880] x B[2880][320]. Tile 128(M) x 160(N),
// 4 waves 2(M)x2(N), wave = 64x80 = 4x5 of 16x16x64 i8.
//
// Round-5 post-mortem: clean 3-deep B pipeline reached ~37us conv (out of
// rocprof top-5). Remaining gap to the 15.3us MFMA floor is NOT a pipe
// ceiling (L2 ~35%, LDS ~45%, MFMA ~42% of their ceilings) and NOT vmcnt
// depth (3-deep = ~2,400cy cover >> ~400cy loaded-L2 latency). Diagnosis:
// the 2 waves/SIMD run the same barrier-synced schedule IN PHASE -- their
// MFMA clusters collide on the matrix pipe, then both stall together on
// operand issue. Fix = T5: s_setprio(1) around the MFMA cluster gives the
// computing wave priority so the other wave drains its load-issue phase ->
// waves anti-phase (catalog: +21-39% on phase-split GEMM schedules,
// m218b/m224). Also: A prefetch deepened to 2 taps (aC/aN/aN2; taps 7-8
// cannot cross the barrier, 2 exposed ds_reads/chunk accepted).
#define CHUNK_SLOTS 1056           // 4 rows * 66 cols * 4 sub-chunks
#define ROUNDS 5                   // ceil(1056 / 256)
#define BUF_BYTES (ROUNDS * 256 * 16)   // 20,480 B per buffer

// One chunk's compute. LAST_ must be a literal 0/1 so every guard below is
// compile-time (tp is unroll-constant): rotations stay SSA renames.
#define CHUNK_BODY(c_, LAST_)                                                   \
{                                                                               \
    const int c__ = (c_);                                                       \
    const unsigned char* ab = Al + (c__ & 1) * BUF_BYTES;                       \
    /* A(tap0), A(tap1): chunk-start ds_reads (cannot prefetch across the */    \
    /* barrier -- other buffer unsafe until the drain). */                      \
    _Pragma("unroll")                                                           \
    for (int mi = 0; mi < 4; ++mi)                                              \
        aC[mi] = *(const v4i*)(ab + wm * 4224 + aoffs[0][mi]);                  \
    _Pragma("unroll")                                                           \
    for (int mi = 0; mi < 4; ++mi)                                              \
        aN[mi] = *(const v4i*)(ab + wm * 4224 + aoffs[1][mi]);                  \
    _Pragma("unroll")                                                           \
    for (int tp = 0; tp < 9; ++tp) {                                            \
        v4i bT[5];                                                              \
        v4i aT[4];                                                              \
        if (tp < 6) {               /* b(tp+3) of this chunk */                 \
            _Pragma("unroll")                                                   \
            for (int ni = 0; ni < 5; ++ni)                                      \
                bT[ni] = *(const v4i*)(bbase[ni] + ((tp + 3) * 5 + c__) * 1024);\
        } else if (!LAST_) {        /* b(tp-6) of next chunk */                 \
            _Pragma("unroll")                                                   \
            for (int ni = 0; ni < 5; ++ni)                                      \
                bT[ni] = *(const v4i*)(bbase[ni] + ((tp - 6) * 5 + (c__ + 1)) * 1024);\
        }                                                                       \
        if (!LAST_ && tp == 0) {    /* stage chunk c+1 AFTER b3's issue */      \
            unsigned char* dst = Al + ((c__ + 1) & 1) * BUF_BYTES;              \
            int cio = (c__ + 1) * 64;                                           \
            _Pragma("unroll")                                                   \
            for (int r = 0; r < ROUNDS; ++r)                                    \
                __builtin_amdgcn_global_load_lds(                               \
                    (gas_uptr)(const void*)(xpad + srcoff[r] + cio),            \
                    (las_uptr)(dst + r * 4096 + t * 16), 16, 0, 0);             \
        }                                                                       \
        if (tp < 7) {               /* A 2-deep prefetch: a(tp+2) */            \
            int tn  = tp + 2;                                                   \
            int kh2 = tn / 3;                                                   \
            int kw2 = tn - kh2 * 3;                                             \
            _Pragma("unroll")                                                   \
            for (int mi = 0; mi < 4; ++mi)                                      \
                aT[mi] = *(const v4i*)(ab + (wm + kh2) * 4224 + aoffs[kw2][mi]);\
        }                                                                       \
        /* T5: prioritize this wave through its MFMA cluster so the other */    \
        /* wave on the SIMD drains its load-issue phase -> anti-phasing.  */    \
        __builtin_amdgcn_s_setprio(1);                                          \
        _Pragma("unroll")                                                       \
        for (int mi = 0; mi < 4; ++mi)                                          \
            _Pragma("unroll")                                                   \
            for (int ni = 0; ni < 5; ++ni)                                      \
                acc[mi][ni] = __builtin_amdgcn_mfma_i32_16x16x64_i8(            \
                    aC[mi], bC[ni], acc[mi][ni], 0, 0, 0);                      \
        __builtin_amdgcn_s_setprio(0);                                          \
        /* rotations: ALL guards compile-time -> pure renames */                \
        if (tp < 8) {                                                           \
            _Pragma("unroll")                                                   \
            for (int mi = 0; mi < 4; ++mi) aC[mi] = aN[mi];                     \
        }                                                                       \
        if (tp < 7) {                                                           \
            _Pragma("unroll")                                                   \
            for (int mi = 0; mi < 4; ++mi) aN[mi] = aT[mi];                     \
        }                                                                       \
        _Pragma("unroll")                                                       \
        for (int ni = 0; ni < 5; ++ni) bC[ni] = bN[ni];                         \
        _Pragma("unroll")                                                       \
        for (int ni = 0; ni < 5; ++ni) bN[ni] = bN2[ni];                        \
        if (tp < 6 || !LAST_) {                                                 \
            _Pragma("unroll")                                                   \
            for (int ni = 0; ni < 5; ++ni) bN2[ni] = bT[ni];                    \
        }                                                                       \
    }                                                                           \
}

__global__ __launch_bounds__(256, 2) void conv_gemm_kernel(const unsigned char* __restrict__ xpad,
                                                           const unsigned char* __restrict__ w8,
                                                           const float* __restrict__ scale,
                                                           const float* __restrict__ be,
                                                           float* __restrict__ out) {
    __shared__ __align__(16) unsigned char Al[2 * BUF_BYTES];   // 40,960 B

    int t    = threadIdx.x;
    int lane = t & 63;
    int wave = t >> 6;
    int wm   = wave & 1;           // M half (64 pixels)
    int wn   = wave >> 1;          // N half (80 couts)
    int m0   = blockIdx.x * 128;   // M fastest; N-pair blocks differ by 256 = same XCD
    int n0   = blockIdx.y * 160;
    int b0   = m0 >> 12;
    int h0   = (m0 & 4095) >> 6;   // first output row of this 2-row tile

    // --- staging source offsets: slot = r*256+t -> (R,C,ql); source sub-chunk
    //     pre-swizzled: qs = ql ^ ((C>>1)&3). Slots >= 1056 clamp to slot 0.
    int srcoff[ROUNDS];
    #pragma unroll
    for (int r = 0; r < ROUNDS; ++r) {
        int slot = r * 256 + t;
        if (slot >= CHUNK_SLOTS) slot = 0;
        int R   = slot / 264;                 // 66 cols * 4 sub-chunks per row
        int rem = slot - R * 264;
        int C   = rem >> 2;
        int ql  = rem & 3;
        int qs  = ql ^ ((C >> 1) & 3);
        srcoff[r] = ((b0 * HP + h0 + R) * WP + C) * CIN + qs * 16;
    }

    int colc = lane & 15;
    int q    = lane >> 4;

    // --- A fragment LDS offsets (per kw, per mi); row term (wm+kh)*4224 added
    //     at use. Phase-uniform swizzle: within any 16-lane quarter-wave,
    //     slot-group = 4(C&1) + q^((C>>1)&3) covers all 8 bank-groups twice.
    int aoffs[3][4];
    #pragma unroll
    for (int kw = 0; kw < 3; ++kw)
        #pragma unroll
        for (int mi = 0; mi < 4; ++mi) {
            int C = mi * 16 + colc + kw;
            aoffs[kw][mi] = C * 64 + ((q ^ ((C >> 1) & 3)) * 16);
        }

    // --- B fragment base pointers: fragment-linear w8, one contiguous 1KiB
    //     per (coT, tap, chunk); offset (tap*5+chunk)*1024 at use.
    const unsigned char* bbase[5];
    int coT0 = (n0 >> 4) + wn * 5;
    #pragma unroll
    for (int ni = 0; ni < 5; ++ni)
        bbase[ni] = w8 + (size_t)(coT0 + ni) * (45 * 1024) + lane * 16;

    v4i acc[4][5];
    v4i zero = {0, 0, 0, 0};
    #pragma unroll
    for (int mi = 0; mi < 4; ++mi)
        #pragma unroll
        for (int ni = 0; ni < 5; ++ni) acc[mi][ni] = zero;

    // --- prologue: B(tap0/1/2, chunk0) prefetch + stage ci-chunk 0 ---
    v4i bC[5], bN[5], bN2[5], aC[4], aN[4];
    #pragma unroll
    for (int ni = 0; ni < 5; ++ni) bC[ni]  = *(const v4i*)(bbase[ni]);
    #pragma unroll
    for (int ni = 0; ni < 5; ++ni) bN[ni]  = *(const v4i*)(bbase[ni] + 5 * 1024);
    #pragma unroll
    for (int ni = 0; ni < 5; ++ni) bN2[ni] = *(const v4i*)(bbase[ni] + 10 * 1024);
    #pragma unroll
    for (int r = 0; r < ROUNDS; ++r)
        __builtin_amdgcn_global_load_lds((gas_uptr)(const void*)(xpad + srcoff[r]),
                                         (las_uptr)(Al + r * 4096 + t * 16), 16, 0, 0);
    __syncthreads();

    #pragma unroll 1
    for (int c = 0; c < 4; ++c) {
        CHUNK_BODY(c, 0)
        __syncthreads();   // reads of buf[c&1] done; stage(c+1) + b0..b2 drained
    }
    CHUNK_BODY(4, 1)       // peeled: no staging, no next-chunk B, static guards

    // Epilogue: C/D layout col = lane&15 (co), row = q*4 + reg (pixel).
    #pragma unroll
    for (int ni = 0; ni < 5; ++ni) {
        int co = n0 + wn * 80 + ni * 16 + colc;
        float s  = scale[co];
        float bz = be[co];
        #pragma unroll
        for (int mi = 0; mi < 4; ++mi) {
            int pix = m0 + wm * 64 + mi * 16 + q * 4;
            int bb2 = pix >> 12;
            int hw  = pix & 4095;
            v4i v = acc[mi][ni];
            float4 o;
            o.x = s * (float)v.x + bz;
            o.y = s * (float)v.y + bz;
            o.z = s * (float)v.z + bz;
            o.w = s * (float)v.w + bz;
            *(float4*)(out + (size_t)(bb2 * COUT + co) * HW_ + hw) = o;
        }
    }
}

// ---------------------------------------------------------------------------
extern "C" void kernel_launch(void* const* d_in, const int* in_sizes, int n_in,
                              void* d_out, int out_size, void* d_ws, size_t ws_size,
                              hipStream_t stream) {
    const float* x     = (const float*)d_in[0];
    const int*   wint  = (const int*)d_in[1];
    const float* wsum  = (const float*)d_in[2];
    const float* scale = (const float*)d_in[3];
    const float* inv_p = (const float*)d_in[4];
    const float* zp_p  = (const float*)d_in[5];
    const float* bias  = (const float*)d_in[6];
    float* out = (float*)d_out;

    unsigned char* xpad = (unsigned char*)d_ws;
    unsigned char* w8   = xpad + XPAD_BYTES;
    float*         be   = (float*)(w8 + W8_BYTES);

    repack_bias_kernel<<<(COUT * 720) / 256, 256, 0, stream>>>(wint, w8, wsum, scale, bias, zp_p, be);
    quant_pad_kernel<<<B_ * HP, 256, 0, stream>>>(x, xpad, inv_p, zp_p);

    dim3 grid((B_ * H_ * W_) / 128, COUT / 160);      // 256 x 2, M fastest
    conv_gemm_kernel<<<grid, 256, 0, stream>>>(xpad, w8, scale, be, out);
}

// Round 7
// 134.207 us; speedup vs baseline: 1.0718x; 1.0055x over previous
//
#include <hip/hip_runtime.h>
#include <hip/hip_bf16.h>

// QuantizedConv2d: B=8, Cin=Cout=320, H=W=64, K=3, stride=1, pad=1.
// out = scale[co] * conv_zp_padded_int8(x_int, W) + bias_eff[co]
// bias_eff[co] = bias[co] - scale[co]*zp*sum(W[co]); x padded with zp byte.

typedef int v4i __attribute__((ext_vector_type(4)));

typedef const unsigned int __attribute__((address_space(1)))* gas_uptr;
typedef unsigned int __attribute__((address_space(3)))* las_uptr;

#define B_   8
#define CIN  320
#define COUT 320
#define H_   64
#define W_   64
#define HW_  4096
#define HP   66
#define WP   66
#define XPAD_BYTES (B_*HP*WP*CIN)
#define W8_BYTES (COUT*9*CIN)

// ---------------------------------------------------------------------------
// Kernel 1: weight repack int32 [O][I][3][3] -> FRAGMENT-LINEAR int8 layout
//   w8[coT(20)][tap(9)][chunk(5)][lane(64)][16B],  lane = q*16 + colc,
//   holding bytes w_orig[co = coT*16+colc][tap][ci = chunk*64 + q*16 .. +16].
// One B-fragment wave-load = one contiguous aligned 1KiB burst. (unchanged)
__global__ __launch_bounds__(256) void repack_bias_kernel(const int* __restrict__ wint,
                                                          unsigned char* __restrict__ w8,
                                                          const float* __restrict__ wsum,
                                                          const float* __restrict__ scale,
                                                          const float* __restrict__ bias,
                                                          const float* __restrict__ zp_p,
                                                          float* __restrict__ be) {
    int j = blockIdx.x * 256 + threadIdx.x;     // < 230,400 dwords
    if (j < COUT) {
        float s = 0.f;
        #pragma unroll
        for (int tp = 0; tp < 9; ++tp) s += wsum[j*9 + tp];
        be[j] = bias[j] - scale[j] * zp_p[0] * s;
    }
    int co  = j / 720;
    int r   = j - co * 720;                     // tap*80 + d
    int tap = r / 80;
    int d   = r - tap * 80;
    int ci  = d * 4;
    const int* base = wint + (co * CIN + ci) * 9 + tap;
    unsigned b0 = (unsigned)(base[0]  & 0xFF);
    unsigned b1 = (unsigned)(base[9]  & 0xFF);
    unsigned b2 = (unsigned)(base[18] & 0xFF);
    unsigned b3 = (unsigned)(base[27] & 0xFF);
    unsigned dword = b0 | (b1 << 8) | (b2 << 16) | (b3 << 24);

    int coT   = co >> 4;
    int colc  = co & 15;
    int chunk = ci >> 6;
    int q     = (ci >> 4) & 3;
    int dw    = (ci >> 2) & 3;
    int lane  = q * 16 + colc;
    int idx   = (((coT * 9 + tap) * 5 + chunk) * 64 + lane) * 4 + dw;
    ((unsigned*)w8)[idx] = dword;
}

// ---------------------------------------------------------------------------
// Kernel 2: quantize + pad (register transpose; LDS dword writes stride 81).
// (unchanged)
__global__ __launch_bounds__(256) void quant_pad_kernel(const float* __restrict__ x,
                                                        unsigned char* __restrict__ xpad,
                                                        const float* __restrict__ inv_p,
                                                        const float* __restrict__ zp_p) {
    __shared__ __align__(16) unsigned lds[64 * 81];
    int bid = blockIdx.x;
    int b  = bid / HP;
    int ph = bid - b * HP;
    int t  = threadIdx.x;
    float inv = inv_p[0];
    float zp  = zp_p[0];
    int zpi = (int)rintf(zp);
    unsigned zd = ((unsigned)(zpi & 0xFF)) * 0x01010101u;

    unsigned* rowbase = (unsigned*)(xpad + (size_t)((b * HP + ph) * WP) * CIN);

    if (ph == 0 || ph == HP - 1) {
        for (int j = t; j < WP * CIN / 4; j += 256) rowbase[j] = zd;
        return;
    }
    int h = ph - 1;
    const float* xrow = x + (size_t)b * CIN * H_ * W_ + h * W_;
    int wq = t & 15;
    int cg = t >> 4;
    #pragma unroll
    for (int i = 0; i < 5; ++i) {
        int ci0 = i * 64 + cg * 4;
        float4 f[4];
        #pragma unroll
        for (int jj = 0; jj < 4; ++jj)
            f[jj] = *(const float4*)(xrow + (size_t)(ci0 + jj) * HW_ + wq * 4);
        #pragma unroll
        for (int k = 0; k < 4; ++k) {
            unsigned d = 0;
            #pragma unroll
            for (int jj = 0; jj < 4; ++jj) {
                float v = (&f[jj].x)[k];
                float q = rintf(v * inv) + zp;
                q = fminf(fmaxf(q, -128.0f), 127.0f);
                int qi = (int)q;
                d |= ((unsigned)(qi & 0xFF)) << (8 * jj);
            }
            lds[(wq * 4 + k) * 81 + (ci0 >> 2)] = d;
        }
    }
    __syncthreads();
    if (t < 80)            rowbase[t] = zd;
    else if (t < 160)      rowbase[65 * 80 + (t - 80)] = zd;
    for (int j = t; j < 64 * 80; j += 256) {
        int p = j / 80;
        int d = j - p * 80;
        rowbase[80 + j] = lds[p * 81 + d];
    }
}

// ---------------------------------------------------------------------------
// Kernel 3: implicit-GEMM conv -- SAME-WN BLOCK GEOMETRY (B dedupe via L1).
// C[32768][320] = A[32768][2880] x B[2880][320]. Block tile 256(M) x 80(N),
// 4 waves = 4 M-quarters (wm=wave, wn gone); wave = 64x80 = 4x5 of 16x16x64.
//
// Round-6 post-mortem: setprio/anti-phasing gave ~1us (falsifier hit).
// Correct per-CU accounting: B traffic was 360 KiB/chunk/CU (wm-pairs AND
// both co-resident blocks load byte-identical B; the two wn-halves stream
// 90 KiB/chunk through the 32 KiB L1 -> no reuse). At the 7,344cy MFMA
// floor that is ~90% of the ~56 B/cy per-CU L2 return path -- the memory
// path runs parallel-cost with MFMA, so no schedule can converge to the
// floor. THIS version changes geometry, not scheduling: all 4 waves of a
// block share the same 80 couts, so their B loads are byte-identical and
// timing-adjacent; <=15 KiB of B in flight (3-deep x 5 KiB/tap) << 32 KiB
// L1 -> 3 of 4 copies hit L1; B L2 traffic per CU drops ~4x. Wave
// microstructure (acc 4x5, fragment-linear B, 3-deep B / 2-deep A
// pipeline, swizzle, setprio) is unchanged; halo grows to 6 rows.
#define CHUNK_SLOTS 1584           // 6 rows * 66 cols * 4 sub-chunks
#define ROUNDS 7                   // ceil(1584 / 256)
#define BUF_BYTES (ROUNDS * 256 * 16)   // 28,672 B per buffer (25,344 used)

// One chunk's compute. LAST_ must be a literal 0/1 so every guard below is
// compile-time (tp is unroll-constant): rotations stay SSA renames.
#define CHUNK_BODY(c_, LAST_)                                                   \
{                                                                               \
    const int c__ = (c_);                                                       \
    const unsigned char* ab = Al + (c__ & 1) * BUF_BYTES;                       \
    /* A(tap0), A(tap1): chunk-start ds_reads (cannot prefetch across the */    \
    /* barrier -- other buffer unsafe until the drain). */                      \
    _Pragma("unroll")                                                           \
    for (int mi = 0; mi < 4; ++mi)                                              \
        aC[mi] = *(const v4i*)(ab + wm * 4224 + aoffs[0][mi]);                  \
    _Pragma("unroll")                                                           \
    for (int mi = 0; mi < 4; ++mi)                                              \
        aN[mi] = *(const v4i*)(ab + wm * 4224 + aoffs[1][mi]);                  \
    _Pragma("unroll")                                                           \
    for (int tp = 0; tp < 9; ++tp) {                                            \
        v4i bT[5];                                                              \
        v4i aT[4];                                                              \
        if (tp < 6) {               /* b(tp+3) of this chunk */                 \
            _Pragma("unroll")                                                   \
            for (int ni = 0; ni < 5; ++ni)                                      \
                bT[ni] = *(const v4i*)(bbase[ni] + ((tp + 3) * 5 + c__) * 1024);\
        } else if (!LAST_) {        /* b(tp-6) of next chunk */                 \
            _Pragma("unroll")                                                   \
            for (int ni = 0; ni < 5; ++ni)                                      \
                bT[ni] = *(const v4i*)(bbase[ni] + ((tp - 6) * 5 + (c__ + 1)) * 1024);\
        }                                                                       \
        if (!LAST_ && tp == 0) {    /* stage chunk c+1 AFTER b3's issue */      \
            unsigned char* dst = Al + ((c__ + 1) & 1) * BUF_BYTES;              \
            int cio = (c__ + 1) * 64;                                           \
            _Pragma("unroll")                                                   \
            for (int r = 0; r < ROUNDS; ++r)                                    \
                __builtin_amdgcn_global_load_lds(                               \
                    (gas_uptr)(const void*)(xpad + srcoff[r] + cio),            \
                    (las_uptr)(dst + r * 4096 + t * 16), 16, 0, 0);             \
        }                                                                       \
        if (tp < 7) {               /* A 2-deep prefetch: a(tp+2) */            \
            int tn  = tp + 2;                                                   \
            int kh2 = tn / 3;                                                   \
            int kw2 = tn - kh2 * 3;                                             \
            _Pragma("unroll")                                                   \
            for (int mi = 0; mi < 4; ++mi)                                      \
                aT[mi] = *(const v4i*)(ab + (wm + kh2) * 4224 + aoffs[kw2][mi]);\
        }                                                                       \
        /* T5: keep wave-priority through the MFMA cluster. */                  \
        __builtin_amdgcn_s_setprio(1);                                          \
        _Pragma("unroll")                                                       \
        for (int mi = 0; mi < 4; ++mi)                                          \
            _Pragma("unroll")                                                   \
            for (int ni = 0; ni < 5; ++ni)                                      \
                acc[mi][ni] = __builtin_amdgcn_mfma_i32_16x16x64_i8(            \
                    aC[mi], bC[ni], acc[mi][ni], 0, 0, 0);                      \
        __builtin_amdgcn_s_setprio(0);                                          \
        /* rotations: ALL guards compile-time -> pure renames */                \
        if (tp < 8) {                                                           \
            _Pragma("unroll")                                                   \
            for (int mi = 0; mi < 4; ++mi) aC[mi] = aN[mi];                     \
        }                                                                       \
        if (tp < 7) {                                                           \
            _Pragma("unroll")                                                   \
            for (int mi = 0; mi < 4; ++mi) aN[mi] = aT[mi];                     \
        }                                                                       \
        _Pragma("unroll")                                                       \
        for (int ni = 0; ni < 5; ++ni) bC[ni] = bN[ni];                         \
        _Pragma("unroll")                                                       \
        for (int ni = 0; ni < 5; ++ni) bN[ni] = bN2[ni];                        \
        if (tp < 6 || !LAST_) {                                                 \
            _Pragma("unroll")                                                   \
            for (int ni = 0; ni < 5; ++ni) bN2[ni] = bT[ni];                    \
        }                                                                       \
    }                                                                           \
}

__global__ __launch_bounds__(256, 2) void conv_gemm_kernel(const unsigned char* __restrict__ xpad,
                                                           const unsigned char* __restrict__ w8,
                                                           const float* __restrict__ scale,
                                                           const float* __restrict__ be,
                                                           float* __restrict__ out) {
    __shared__ __align__(16) unsigned char Al[2 * BUF_BYTES];   // 57,344 B

    int t    = threadIdx.x;
    int lane = t & 63;
    int wave = t >> 6;
    int wm   = wave;               // M quarter (64 pixels each); all waves share N
    int m0   = blockIdx.x * 256;   // 4 image rows of one batch image
    int n0   = blockIdx.y * 80;
    int b0   = m0 >> 12;
    int h0   = (m0 & 4095) >> 6;   // first output row of this 4-row tile

    // --- staging source offsets: slot = r*256+t -> (R,C,ql); source sub-chunk
    //     pre-swizzled: qs = ql ^ ((C>>1)&3). Slots >= 1584 clamp to slot 0
    //     (dup fetch = L1 hit; garbage lands in the dead LDS tail 25344..28671).
    int srcoff[ROUNDS];
    #pragma unroll
    for (int r = 0; r < ROUNDS; ++r) {
        int slot = r * 256 + t;
        if (slot >= CHUNK_SLOTS) slot = 0;
        int R   = slot / 264;                 // 66 cols * 4 sub-chunks per row
        int rem = slot - R * 264;
        int C   = rem >> 2;
        int ql  = rem & 3;
        int qs  = ql ^ ((C >> 1) & 3);
        srcoff[r] = ((b0 * HP + h0 + R) * WP + C) * CIN + qs * 16;
    }

    int colc = lane & 15;
    int q    = lane >> 4;

    // --- A fragment LDS offsets (per kw, per mi); row term (wm+kh)*4224 added
    //     at use (wm 0..3, kh 0..2 -> rows 0..5). Phase-uniform swizzle:
    //     within any 16-lane quarter-wave, slot-group = 4(C&1) + q^((C>>1)&3)
    //     covers all 8 bank-groups exactly twice.
    int aoffs[3][4];
    #pragma unroll
    for (int kw = 0; kw < 3; ++kw)
        #pragma unroll
        for (int mi = 0; mi < 4; ++mi) {
            int C = mi * 16 + colc + kw;
            aoffs[kw][mi] = C * 64 + ((q ^ ((C >> 1) & 3)) * 16);
        }

    // --- B fragment base pointers: fragment-linear w8, one contiguous 1KiB
    //     per (coT, tap, chunk). IDENTICAL across the block's 4 waves ->
    //     timing-adjacent duplicate loads hit L1.
    const unsigned char* bbase[5];
    int coT0 = n0 >> 4;
    #pragma unroll
    for (int ni = 0; ni < 5; ++ni)
        bbase[ni] = w8 + (size_t)(coT0 + ni) * (45 * 1024) + lane * 16;

    v4i acc[4][5];
    v4i zero = {0, 0, 0, 0};
    #pragma unroll
    for (int mi = 0; mi < 4; ++mi)
        #pragma unroll
        for (int ni = 0; ni < 5; ++ni) acc[mi][ni] = zero;

    // --- prologue: B(tap0/1/2, chunk0) prefetch + stage ci-chunk 0 ---
    v4i bC[5], bN[5], bN2[5], aC[4], aN[4];
    #pragma unroll
    for (int ni = 0; ni < 5; ++ni) bC[ni]  = *(const v4i*)(bbase[ni]);
    #pragma unroll
    for (int ni = 0; ni < 5; ++ni) bN[ni]  = *(const v4i*)(bbase[ni] + 5 * 1024);
    #pragma unroll
    for (int ni = 0; ni < 5; ++ni) bN2[ni] = *(const v4i*)(bbase[ni] + 10 * 1024);
    #pragma unroll
    for (int r = 0; r < ROUNDS; ++r)
        __builtin_amdgcn_global_load_lds((gas_uptr)(const void*)(xpad + srcoff[r]),
                                         (las_uptr)(Al + r * 4096 + t * 16), 16, 0, 0);
    __syncthreads();

    #pragma unroll 1
    for (int c = 0; c < 4; ++c) {
        CHUNK_BODY(c, 0)
        __syncthreads();   // reads of buf[c&1] done; stage(c+1) + b0..b2 drained
    }
    CHUNK_BODY(4, 1)       // peeled: no staging, no next-chunk B, static guards

    // Epilogue: C/D layout col = lane&15 (co), row = q*4 + reg (pixel).
    #pragma unroll
    for (int ni = 0; ni < 5; ++ni) {
        int co = n0 + ni * 16 + colc;
        float s  = scale[co];
        float bz = be[co];
        #pragma unroll
        for (int mi = 0; mi < 4; ++mi) {
            int pix = m0 + wm * 64 + mi * 16 + q * 4;
            int bb2 = pix >> 12;
            int hw  = pix & 4095;
            v4i v = acc[mi][ni];
            float4 o;
            o.x = s * (float)v.x + bz;
            o.y = s * (float)v.y + bz;
            o.z = s * (float)v.z + bz;
            o.w = s * (float)v.w + bz;
            *(float4*)(out + (size_t)(bb2 * COUT + co) * HW_ + hw) = o;
        }
    }
}

// ---------------------------------------------------------------------------
extern "C" void kernel_launch(void* const* d_in, const int* in_sizes, int n_in,
                              void* d_out, int out_size, void* d_ws, size_t ws_size,
                              hipStream_t stream) {
    const float* x     = (const float*)d_in[0];
    const int*   wint  = (const int*)d_in[1];
    const float* wsum  = (const float*)d_in[2];
    const float* scale = (const float*)d_in[3];
    const float* inv_p = (const float*)d_in[4];
    const float* zp_p  = (const float*)d_in[5];
    const float* bias  = (const float*)d_in[6];
    float* out = (float*)d_out;

    unsigned char* xpad = (unsigned char*)d_ws;
    unsigned char* w8   = xpad + XPAD_BYTES;
    float*         be   = (float*)(w8 + W8_BYTES);

    repack_bias_kernel<<<(COUT * 720) / 256, 256, 0, stream>>>(wint, w8, wsum, scale, bias, zp_p, be);
    quant_pad_kernel<<<B_ * HP, 256, 0, stream>>>(x, xpad, inv_p, zp_p);

    dim3 grid((B_ * H_ * W_) / 256, COUT / 80);       // 128 x 4 = 512 blocks
    conv_gemm_kernel<<<grid, 256, 0, stream>>>(xpad, w8, scale, be, out);
}